// Round 13
// baseline (97.378 us; speedup 1.0000x reference)
//
#include <hip/hip_runtime.h>

#define LSEQ 384
#define EMBED 1280
#define HID 256
#define NBINS 10
#define GM 768           // B*L rows
#define KP 512           // packed K: 2 signs x HID
#define NJN (LSEQ * NBINS)   // 3840 jn-columns per batch
#define NKX (EMBED / 32)     // 40 k-chunks, stage 1
#define NKP (KP / 32)        // 16 k-chunks, stage 2

typedef __attribute__((ext_vector_type(8))) short short8;
typedef __attribute__((ext_vector_type(4))) float float4v;

__device__ __forceinline__ unsigned bfbits(float f) {
    unsigned u = __builtin_bit_cast(unsigned, f);
    return (u + 0x7fffu + ((u >> 16) & 1u)) >> 16;   // RNE
}

// Fragment-major layout: chunk(rt, kc) = 1KB = [lane64][8 bf16];
// lane = (row%16) + 16*((k%32)/8); rt = row/16, kc = k/32.

// ---------------- P: xb_f frag-major [48rt][40kc]; WT_f frag-major [32rt][40kc]
__global__ __launch_bounds__(256) void k_prep(
    const float* __restrict__ x, const float* __restrict__ Wi, const float* __restrict__ Wj,
    short* __restrict__ xb_f, short* __restrict__ WT_f)
{
    __shared__ float tile[32][33];
    const int t = threadIdx.x;
    int bx = blockIdx.x;
    if (bx < 480) {                       // x -> xb_f, 4 chunks per block
        const int cid = bx * 4 + (t >> 6);
        const int rt = cid / NKX, kc = cid - rt * NKX;
        const int lane = t & 63;
        const int row = rt * 16 + (lane & 15);
        const int k = kc * 32 + (lane >> 4) * 8;
        const float4v a = *(const float4v*)(x + (size_t)row * EMBED + k);
        const float4v b = *(const float4v*)(x + (size_t)row * EMBED + k + 4);
        short8 o;
        o[0] = (short)bfbits(a.x); o[1] = (short)bfbits(a.y);
        o[2] = (short)bfbits(a.z); o[3] = (short)bfbits(a.w);
        o[4] = (short)bfbits(b.x); o[5] = (short)bfbits(b.y);
        o[6] = (short)bfbits(b.z); o[7] = (short)bfbits(b.w);
        *(short8*)(xb_f + (size_t)cid * 512 + lane * 8) = o;
    } else {                              // W transpose -> WT_f
        bx -= 480;
        const int isJ = bx >= 320 ? 1 : 0;
        if (isJ) bx -= 320;
        const int tk = bx % 40, tn = bx / 40;
        const int k0 = tk * 32, n0 = tn * 32;
        const float* __restrict__ W = isJ ? Wj : Wi;
        const int r = t >> 3, c4 = (t & 7) * 4;
        const float4v v = *(const float4v*)(W + (size_t)(k0 + r) * HID + n0 + c4);
        tile[r][c4 + 0] = v.x; tile[r][c4 + 1] = v.y;
        tile[r][c4 + 2] = v.z; tile[r][c4 + 3] = v.w;
        __syncthreads();
        const int chunkhalf = t >> 7;             // which 16-n group
        const int l = (t & 127) >> 1;             // lane in chunk
        const int hs = t & 1;                     // 8B half
        const int n_loc = chunkhalf * 16 + (l & 15);
        const int k_loc = (l >> 4) * 8 + hs * 4;
        const int rt = isJ * 16 + tn * 2 + chunkhalf;
        unsigned d0 = bfbits(tile[k_loc + 0][n_loc]) | (bfbits(tile[k_loc + 1][n_loc]) << 16);
        unsigned d1 = bfbits(tile[k_loc + 2][n_loc]) | (bfbits(tile[k_loc + 3][n_loc]) << 16);
        unsigned* dst = (unsigned*)(WT_f + ((size_t)rt * NKX + tk) * 512 + l * 8 + hs * 4);
        dst[0] = d0; dst[1] = d1;
    }
}

// ---------------- G: C[768,512] = xb @ [Wi|Wj]^T; fused epilogues:
//   i-half (n0<256) -> A_f frag-major [48rt][16kc] = relu+-(xi)
//   j-half          -> Bp_f frag-major directly: relu+-(xj)[j][h] * Wo[h][n]
// LDS-free K-loop, coalesced 1KB frag loads. grid (24,16), 4-wave quadrants.
__global__ __launch_bounds__(256) void k_gemm_pack(
    const short* __restrict__ xb_f, const short* __restrict__ WT_f,
    const float* __restrict__ bi, const float* __restrict__ bj, const float* __restrict__ Wo,
    short* __restrict__ A_f, short* __restrict__ Bp_f)
{
    __shared__ float sC[32][33];
    __shared__ float woS[32 * NBINS];
    const int tid = threadIdx.x;
    const int lane = tid & 63, w = tid >> 6;
    const int mh = w & 1, nh = w >> 1;
    const int l15 = lane & 15, q = lane >> 4;
    const int m0 = blockIdx.x * 32, n0 = blockIdx.y * 32;
    const bool isI = (n0 < HID);

    if (!isI) {   // Wo rows h0..h0+32 = 320 contiguous floats
        for (int i = tid; i < 32 * NBINS; i += 256) woS[i] = Wo[(n0 - HID) * NBINS + i];
    }

    const short* ap = xb_f + ((size_t)(blockIdx.x * 2 + mh) * NKX) * 512 + lane * 8;
    const short* bp = WT_f + ((size_t)(blockIdx.y * 2 + nh) * NKX) * 512 + lane * 8;

    float4v acc = {0.f, 0.f, 0.f, 0.f};
#pragma unroll 5
    for (int ks = 0; ks < NKX; ++ks) {
        const short8 af = *(const short8*)(ap + ks * 512);
        const short8 bf = *(const short8*)(bp + ks * 512);
        acc = __builtin_amdgcn_mfma_f32_16x16x32_bf16(af, bf, acc, 0, 0, 0);
    }

    const int nloc = nh * 16 + l15;
    const float bv = isI ? bi[n0 + nloc] : bj[n0 - HID + nloc];
#pragma unroll
    for (int r = 0; r < 4; ++r)
        sC[mh * 16 + q * 4 + r][nloc] = acc[r] + bv;
    __syncthreads();

    if (isI) {
        // 4 chunks: (g m-group) x (sign); fully coalesced 1KB stores
        const int g = tid >> 7, sign = (tid >> 6) & 1, l = tid & 63;
        const int mr = g * 16 + (l & 15);
        const int kq = (l >> 4) * 8;
        short8 o;
#pragma unroll
        for (int c = 0; c < 8; ++c) {
            const float v = sC[mr][kq + c];
            o[c] = (short)bfbits(sign ? fmaxf(-v, 0.f) : fmaxf(v, 0.f));
        }
        const int rt = blockIdx.x * 2 + g;
        const int kc = (n0 >> 5) + sign * 8;
        *(short8*)(A_f + ((size_t)rt * NKP + kc) * 512 + l * 8) = o;
    } else {
        // Bp_f pack: 40 chunks = 20 jn-rts x 2 signs, 1KB coalesced stores.
        const int h0 = n0 - HID;
        const int bb = m0 >= LSEQ ? 1 : 0;
        const int jloc0 = m0 - bb * LSEQ;          // j-tile base within batch
        const int rt0 = (jloc0 * NBINS) >> 4;      // exact: 32 | jloc0
        const int l = tid & 63;
        const int c0 = tid >> 6;                   // 0..3
        const int ll15 = l & 15, e8 = (l >> 4) * 8;
#pragma unroll
        for (int s = 0; s < 10; ++s) {
            const int c = s * 4 + c0;              // 0..39
            const int sgn = c & 1, rtl = c >> 1;
            const int jn = (rt0 + rtl) * 16 + ll15;
            const int j = (jn * 6554) >> 16;       // jn/10 for jn<16384
            const int n = jn - j * NBINS;
            const int jl = j - jloc0;              // 0..31
            short8 o;
#pragma unroll
            for (int e = 0; e < 8; ++e) {
                const int hc = e8 + e;
                const float v = sC[jl][hc];
                const float p = sgn ? fmaxf(-v, 0.f) : fmaxf(v, 0.f);
                o[e] = (short)bfbits(p * woS[hc * NBINS + n]);
            }
            const int kc = (h0 >> 5) + sgn * 8;
            *(short8*)(Bp_f + ((size_t)(bb * 240 + rt0 + rtl) * NKP + kc) * 512 + l * 8) = o;
        }
    }
}

// ---------------- K2: out[b][i][jn] = A_f(i) . B'_f(jn) + bo[n]
// GEMM M=384,N=3840,K=512 per batch. Block 128i x 128jn, 4 waves,
// wave = 64i x 64jn (4x4 frags): 8 loads -> 16 MFMAs per ks (2:1).
// LDS-free, no barriers, coalesced 1KB frag loads.
// XCD swizzle: jT pinned to bid%8 so the 6 blocks sharing a jT's B-chunks
// land on ONE XCD. Grid 192 (12 idle).
__global__ __launch_bounds__(256) void k2_pair(
    const short* __restrict__ A_f, const short* __restrict__ Bp_f,
    const float* __restrict__ bo, float* __restrict__ out)
{
    const int bid = blockIdx.x;
    const int c8 = bid & 7, slot = bid >> 3;      // grid 192: slot 0..23
    const int q4 = slot / 6, r6 = slot % 6;
    const int jT = c8 + 8 * q4;                   // 0..31
    if (jT >= 30) return;
    const int iT = r6 % 3, b = r6 / 3;

    const int tid = threadIdx.x;
    const int lane = tid & 63, w = tid >> 6;
    const int iw = w & 1, jw = w >> 1;
    const int l15 = lane & 15, q = lane >> 4;
    const int i0 = iT * 128, jn0 = jT * 128;

    const short* ap = A_f + ((size_t)(b * 24 + (i0 >> 4) + iw * 4) * NKP) * 512 + lane * 8;
    const short* bp = Bp_f + ((size_t)(b * 240 + (jn0 >> 4) + jw * 4) * NKP) * 512 + lane * 8;

    float4v acc[4][4];   // [ia][jb]
#pragma unroll
    for (int ia = 0; ia < 4; ++ia)
#pragma unroll
        for (int jb = 0; jb < 4; ++jb) acc[ia][jb] = (float4v){0.f, 0.f, 0.f, 0.f};

#pragma unroll 2
    for (int ks = 0; ks < NKP; ++ks) {
        short8 af[4], bf[4];
#pragma unroll
        for (int r = 0; r < 4; ++r) {
            af[r] = *(const short8*)(ap + ((size_t)r * NKP + ks) * 512);
            bf[r] = *(const short8*)(bp + ((size_t)r * NKP + ks) * 512);
        }
#pragma unroll
        for (int ia = 0; ia < 4; ++ia)
#pragma unroll
            for (int jb = 0; jb < 4; ++jb)
                acc[ia][jb] = __builtin_amdgcn_mfma_f32_16x16x32_bf16(af[ia], bf[jb], acc[ia][jb], 0, 0, 0);
    }

    // epilogue: direct stores; C layout col=l15, row=q*4+r
#pragma unroll
    for (int jb = 0; jb < 4; ++jb) {
        const int jn = jn0 + jw * 64 + jb * 16 + l15;
        const int jq = (jn * 6554) >> 16;         // jn/10 for jn<16384
        const int n = jn - jq * NBINS;
        const float bv = bo[n];
#pragma unroll
        for (int ia = 0; ia < 4; ++ia) {
            const int i = i0 + iw * 64 + ia * 16 + q * 4;
            float* orow = out + ((size_t)(b * LSEQ + i) * NJN) + jn;
#pragma unroll
            for (int r = 0; r < 4; ++r)
                orow[(size_t)r * NJN] = acc[ia][jb][r] + bv;
        }
    }
}

extern "C" void kernel_launch(void* const* d_in, const int* in_sizes, int n_in,
                              void* d_out, int out_size, void* d_ws, size_t ws_size,
                              hipStream_t stream)
{
    const float* x  = (const float*)d_in[0];
    const float* Wi = (const float*)d_in[1];
    const float* bi = (const float*)d_in[2];
    const float* Wj = (const float*)d_in[3];
    const float* bj = (const float*)d_in[4];
    const float* Wo = (const float*)d_in[5];
    const float* bo = (const float*)d_in[6];
    float* out = (float*)d_out;

    char* p = (char*)d_ws;
    short* xb_f = (short*)p;  p += (size_t)48 * NKX * 512 * 2;        // 1.97 MB
    short* WT_f = (short*)p;  p += (size_t)32 * NKX * 512 * 2;        // 1.31 MB
    short* A_f  = (short*)p;  p += (size_t)48 * NKP * 512 * 2;        // 0.79 MB
    short* Bp_f = (short*)p;                                           // 7.86 MB

    k_prep<<<1120, 256, 0, stream>>>(x, Wi, Wj, xb_f, WT_f);
    k_gemm_pack<<<dim3(GM / 32, 512 / 32), 256, 0, stream>>>(xb_f, WT_f, bi, bj, Wo, A_f, Bp_f);
    k2_pair<<<192, 256, 0, stream>>>(A_f, Bp_f, bo, out);
}

// Round 14
// 93.624 us; speedup vs baseline: 1.0401x; 1.0401x over previous
//
#include <hip/hip_runtime.h>

#define LSEQ 384
#define EMBED 1280
#define HID 256
#define NBINS 10
#define GM 768           // B*L rows
#define KP 512           // packed K: 2 signs x HID
#define NJN (LSEQ * NBINS)   // 3840 jn-columns per batch
#define NKX (EMBED / 32)     // 40 k-chunks, stage 1
#define NKP (KP / 32)        // 16 k-chunks, stage 2

typedef __attribute__((ext_vector_type(8))) short short8;
typedef __attribute__((ext_vector_type(4))) float float4v;

__device__ __forceinline__ unsigned bfbits(float f) {
    unsigned u = __builtin_bit_cast(unsigned, f);
    return (u + 0x7fffu + ((u >> 16) & 1u)) >> 16;   // RNE
}

// Fragment-major layout: chunk(rt, kc) = 1KB = [lane64][8 bf16];
// lane = (row%16) + 16*((k%32)/8); rt = row/16, kc = k/32.

// ---------------- P: xb_f frag-major [48rt][40kc]; WT_f frag-major [32rt][40kc]
__global__ __launch_bounds__(256) void k_prep(
    const float* __restrict__ x, const float* __restrict__ Wi, const float* __restrict__ Wj,
    short* __restrict__ xb_f, short* __restrict__ WT_f)
{
    __shared__ float tile[32][33];
    const int t = threadIdx.x;
    int bx = blockIdx.x;
    if (bx < 480) {                       // x -> xb_f, 4 chunks per block
        const int cid = bx * 4 + (t >> 6);
        const int rt = cid / NKX, kc = cid - rt * NKX;
        const int lane = t & 63;
        const int row = rt * 16 + (lane & 15);
        const int k = kc * 32 + (lane >> 4) * 8;
        const float4v a = *(const float4v*)(x + (size_t)row * EMBED + k);
        const float4v b = *(const float4v*)(x + (size_t)row * EMBED + k + 4);
        short8 o;
        o[0] = (short)bfbits(a.x); o[1] = (short)bfbits(a.y);
        o[2] = (short)bfbits(a.z); o[3] = (short)bfbits(a.w);
        o[4] = (short)bfbits(b.x); o[5] = (short)bfbits(b.y);
        o[6] = (short)bfbits(b.z); o[7] = (short)bfbits(b.w);
        *(short8*)(xb_f + (size_t)cid * 512 + lane * 8) = o;
    } else {                              // W transpose -> WT_f
        bx -= 480;
        const int isJ = bx >= 320 ? 1 : 0;
        if (isJ) bx -= 320;
        const int tk = bx % 40, tn = bx / 40;
        const int k0 = tk * 32, n0 = tn * 32;
        const float* __restrict__ W = isJ ? Wj : Wi;
        const int r = t >> 3, c4 = (t & 7) * 4;
        const float4v v = *(const float4v*)(W + (size_t)(k0 + r) * HID + n0 + c4);
        tile[r][c4 + 0] = v.x; tile[r][c4 + 1] = v.y;
        tile[r][c4 + 2] = v.z; tile[r][c4 + 3] = v.w;
        __syncthreads();
        const int chunkhalf = t >> 7;             // which 16-n group
        const int l = (t & 127) >> 1;             // lane in chunk
        const int hs = t & 1;                     // 8B half
        const int n_loc = chunkhalf * 16 + (l & 15);
        const int k_loc = (l >> 4) * 8 + hs * 4;
        const int rt = isJ * 16 + tn * 2 + chunkhalf;
        unsigned d0 = bfbits(tile[k_loc + 0][n_loc]) | (bfbits(tile[k_loc + 1][n_loc]) << 16);
        unsigned d1 = bfbits(tile[k_loc + 2][n_loc]) | (bfbits(tile[k_loc + 3][n_loc]) << 16);
        unsigned* dst = (unsigned*)(WT_f + ((size_t)rt * NKX + tk) * 512 + l * 8 + hs * 4);
        dst[0] = d0; dst[1] = d1;
    }
}

// ---------------- G: C[768,512] = xb @ [Wi|Wj]^T; fused epilogues:
//   i-half (n0<256) -> A_f frag-major [48rt][16kc] = relu+-(xi)
//   j-half          -> Bp_f frag-major directly: relu+-(xj)[j][h] * Wo[h][n]
// LDS-free K-loop, coalesced 1KB frag loads. grid (24,16), 4-wave quadrants.
// Note: bid = mx + 24*ny keeps same-mx blocks on one XCD (24 % 8 == 0), so the
// larger operand (xb_f) is already XCD-localized.
__global__ __launch_bounds__(256) void k_gemm_pack(
    const short* __restrict__ xb_f, const short* __restrict__ WT_f,
    const float* __restrict__ bi, const float* __restrict__ bj, const float* __restrict__ Wo,
    short* __restrict__ A_f, short* __restrict__ Bp_f)
{
    __shared__ float sC[32][33];
    __shared__ float woS[32 * NBINS];
    const int tid = threadIdx.x;
    const int lane = tid & 63, w = tid >> 6;
    const int mh = w & 1, nh = w >> 1;
    const int l15 = lane & 15, q = lane >> 4;
    const int m0 = blockIdx.x * 32, n0 = blockIdx.y * 32;
    const bool isI = (n0 < HID);

    if (!isI) {   // Wo rows h0..h0+32 = 320 contiguous floats
        for (int i = tid; i < 32 * NBINS; i += 256) woS[i] = Wo[(n0 - HID) * NBINS + i];
    }

    const short* ap = xb_f + ((size_t)(blockIdx.x * 2 + mh) * NKX) * 512 + lane * 8;
    const short* bp = WT_f + ((size_t)(blockIdx.y * 2 + nh) * NKX) * 512 + lane * 8;

    float4v acc = {0.f, 0.f, 0.f, 0.f};
#pragma unroll 5
    for (int ks = 0; ks < NKX; ++ks) {
        const short8 af = *(const short8*)(ap + ks * 512);
        const short8 bf = *(const short8*)(bp + ks * 512);
        acc = __builtin_amdgcn_mfma_f32_16x16x32_bf16(af, bf, acc, 0, 0, 0);
    }

    const int nloc = nh * 16 + l15;
    const float bv = isI ? bi[n0 + nloc] : bj[n0 - HID + nloc];
#pragma unroll
    for (int r = 0; r < 4; ++r)
        sC[mh * 16 + q * 4 + r][nloc] = acc[r] + bv;
    __syncthreads();

    if (isI) {
        // 4 chunks: (g m-group) x (sign); fully coalesced 1KB stores
        const int g = tid >> 7, sign = (tid >> 6) & 1, l = tid & 63;
        const int mr = g * 16 + (l & 15);
        const int kq = (l >> 4) * 8;
        short8 o;
#pragma unroll
        for (int c = 0; c < 8; ++c) {
            const float v = sC[mr][kq + c];
            o[c] = (short)bfbits(sign ? fmaxf(-v, 0.f) : fmaxf(v, 0.f));
        }
        const int rt = blockIdx.x * 2 + g;
        const int kc = (n0 >> 5) + sign * 8;
        *(short8*)(A_f + ((size_t)rt * NKP + kc) * 512 + l * 8) = o;
    } else {
        // Bp_f pack: 40 chunks = 20 jn-rts x 2 signs, 1KB coalesced stores.
        const int h0 = n0 - HID;
        const int bb = m0 >= LSEQ ? 1 : 0;
        const int jloc0 = m0 - bb * LSEQ;          // j-tile base within batch
        const int rt0 = (jloc0 * NBINS) >> 4;      // exact: 32 | jloc0
        const int l = tid & 63;
        const int c0 = tid >> 6;                   // 0..3
        const int ll15 = l & 15, e8 = (l >> 4) * 8;
#pragma unroll
        for (int s = 0; s < 10; ++s) {
            const int c = s * 4 + c0;              // 0..39
            const int sgn = c & 1, rtl = c >> 1;
            const int jn = (rt0 + rtl) * 16 + ll15;
            const int j = (jn * 6554) >> 16;       // jn/10 for jn<16384
            const int n = jn - j * NBINS;
            const int jl = j - jloc0;              // 0..31
            short8 o;
#pragma unroll
            for (int e = 0; e < 8; ++e) {
                const int hc = e8 + e;
                const float v = sC[jl][hc];
                const float p = sgn ? fmaxf(-v, 0.f) : fmaxf(v, 0.f);
                o[e] = (short)bfbits(p * woS[hc * NBINS + n]);
            }
            const int kc = (h0 >> 5) + sgn * 8;
            *(short8*)(Bp_f + ((size_t)(bb * 240 + rt0 + rtl) * NKP + kc) * 512 + l * 8) = o;
        }
    }
}

// ---------------- K2: out[b][i][jn] = A_f(i) . B'_f(jn) + bo[n]
// GEMM M=384,N=3840,K=512 per batch. Block 64i x 128jn, 4 waves,
// wave = 32i x 64jn. LDS-free, no barriers, coalesced 1KB frag loads.
// XCD swizzle: jT == bid%8 (mod 8) so the 12 blocks sharing a jT's B-chunks
// (1MB working set) land on ONE XCD -> B served from that XCD's L2, not L3.
// Grid 384, 24 idle (jT>=30).
__global__ __launch_bounds__(256) void k2_pair(
    const short* __restrict__ A_f, const short* __restrict__ Bp_f,
    const float* __restrict__ bo, float* __restrict__ out)
{
    const int c8 = blockIdx.x & 7, kslot = blockIdx.x >> 3;   // grid 384
    const int jT = c8 + 8 * (kslot / 12);                     // 0..31
    if (jT >= 30) return;
    const int r12 = kslot % 12;
    const int iT = r12 % 6, b = r12 / 6;

    const int tid = threadIdx.x;
    const int lane = tid & 63, w = tid >> 6;
    const int iw = w & 1, jw = w >> 1;
    const int l15 = lane & 15, q = lane >> 4;
    const int i0 = iT * 64, jn0 = jT * 128;

    const short* ap = A_f + ((size_t)(b * 24 + (i0 >> 4) + iw * 2) * NKP) * 512 + lane * 8;
    const short* bp = Bp_f + ((size_t)(b * 240 + (jn0 >> 4) + jw * 4) * NKP) * 512 + lane * 8;

    float4v acc[2][4];
#pragma unroll
    for (int ia = 0; ia < 2; ++ia)
#pragma unroll
        for (int jb = 0; jb < 4; ++jb) acc[ia][jb] = (float4v){0.f, 0.f, 0.f, 0.f};

#pragma unroll 2
    for (int ks = 0; ks < NKP; ++ks) {
        const short8 af0 = *(const short8*)(ap + ks * 512);
        const short8 af1 = *(const short8*)(ap + (NKP + ks) * 512);
        short8 bf[4];
#pragma unroll
        for (int jb = 0; jb < 4; ++jb)
            bf[jb] = *(const short8*)(bp + ((size_t)jb * NKP + ks) * 512);
#pragma unroll
        for (int jb = 0; jb < 4; ++jb) {
            acc[0][jb] = __builtin_amdgcn_mfma_f32_16x16x32_bf16(af0, bf[jb], acc[0][jb], 0, 0, 0);
            acc[1][jb] = __builtin_amdgcn_mfma_f32_16x16x32_bf16(af1, bf[jb], acc[1][jb], 0, 0, 0);
        }
    }

    // epilogue: direct stores; C layout col=l15, row=q*4+r
#pragma unroll
    for (int jb = 0; jb < 4; ++jb) {
        const int jn = jn0 + jw * 64 + jb * 16 + l15;
        const int jq = (jn * 6554) >> 16;
        const int n = jn - jq * NBINS;
        const float bv = bo[n];
#pragma unroll
        for (int ia = 0; ia < 2; ++ia) {
            const int i = i0 + iw * 32 + ia * 16 + q * 4;
            float* orow = out + ((size_t)(b * LSEQ + i) * NJN) + jn;
#pragma unroll
            for (int r = 0; r < 4; ++r)
                orow[(size_t)r * NJN] = acc[ia][jb][r] + bv;
        }
    }
}

extern "C" void kernel_launch(void* const* d_in, const int* in_sizes, int n_in,
                              void* d_out, int out_size, void* d_ws, size_t ws_size,
                              hipStream_t stream)
{
    const float* x  = (const float*)d_in[0];
    const float* Wi = (const float*)d_in[1];
    const float* bi = (const float*)d_in[2];
    const float* Wj = (const float*)d_in[3];
    const float* bj = (const float*)d_in[4];
    const float* Wo = (const float*)d_in[5];
    const float* bo = (const float*)d_in[6];
    float* out = (float*)d_out;

    char* p = (char*)d_ws;
    short* xb_f = (short*)p;  p += (size_t)48 * NKX * 512 * 2;        // 1.97 MB
    short* WT_f = (short*)p;  p += (size_t)32 * NKX * 512 * 2;        // 1.31 MB
    short* A_f  = (short*)p;  p += (size_t)48 * NKP * 512 * 2;        // 0.79 MB
    short* Bp_f = (short*)p;                                           // 7.86 MB

    k_prep<<<1120, 256, 0, stream>>>(x, Wi, Wj, xb_f, WT_f);
    k_gemm_pack<<<dim3(GM / 32, 512 / 32), 256, 0, stream>>>(xb_f, WT_f, bi, bj, Wo, A_f, Bp_f);
    k2_pair<<<384, 256, 0, stream>>>(A_f, Bp_f, bo, out);
}